// Round 7
// baseline (333.612 us; speedup 1.0000x reference)
//
#include <hip/hip_runtime.h>
#include <hip/hip_fp16.h>

namespace {
constexpr int kB  = 2;
constexpr int kL  = 1024;
constexpr int kDM = 1024;
constexpr int kDI = 2048;
constexpr int kDPROJ = 8224;   // [x 0..2048 | z ..4096 | B ..6144 | C ..8192 | dt ..8224] (permuted)
constexpr int kBL = 2048;
constexpr int kQ  = 64;
constexpr int kNC = 16;
constexpr int kCvtX = kBL * kDM / 4;
constexpr int kCvtW = kDPROJ * kDM / 4;
constexpr int kCvtO = kDM * kDI / 4;
constexpr int kCvtBlocks  = (kCvtX + kCvtW + kCvtO + 255) / 256;
constexpr int kDtBlocks   = 512;
constexpr int kNegABlocks = 8;
}

typedef float f4 __attribute__((ext_vector_type(4)));
typedef _Float16 f16x8 __attribute__((ext_vector_type(8)));
typedef _Float16 f16x4 __attribute__((ext_vector_type(4)));

__device__ __forceinline__ void async_ld16(const void* g, void* l) {
  __builtin_amdgcn_global_load_lds(
      (const __attribute__((address_space(1))) void*)g,
      (__attribute__((address_space(3))) void*)l, 16, 0, 0);
}

// ---------------------------------------------------------------------------
// K1: f32->f16 cvt of x / W_in(row-PERMUTED) / W_out + f32 dt-GEMM + negA.
// ---------------------------------------------------------------------------
__global__ __launch_bounds__(256) void prep_inputs(
    const float* __restrict__ x, const float* __restrict__ W_in,
    const float* __restrict__ W_out, const float* __restrict__ A_log,
    const float* __restrict__ dt_bias, _Float16* __restrict__ x16,
    _Float16* __restrict__ Wi16, _Float16* __restrict__ Wo16,
    float* __restrict__ dtb, float* __restrict__ negA) {
  const int bid = blockIdx.x;
  const int tid = threadIdx.x;
  if (bid < kCvtBlocks) {
    int i = bid * 256 + tid;
    if (i < kCvtX) {
      const f4 v = ((const f4*)x)[i];
      f16x4 o; o[0]=(_Float16)v[0]; o[1]=(_Float16)v[1]; o[2]=(_Float16)v[2]; o[3]=(_Float16)v[3];
      ((f16x4*)x16)[i] = o;
    } else if (i < kCvtX + kCvtW) {
      i -= kCvtX;
      const int row = i >> 8;
      const int cv  = i & 255;
      int srow;
      if (row < 4096)      srow = row;
      else if (row < 6144) { const int m = row - 4096; srow = 4096 + (m >> 6) * 129 + (m & 63); }
      else if (row < 8192) { const int m = row - 6144; srow = 4096 + (m >> 6) * 129 + 64 + (m & 63); }
      else                 srow = 4096 + (row - 8192) * 129 + 128;
      const f4 v = ((const f4*)(W_in + (size_t)srow * kDM))[cv];
      f16x4 o; o[0]=(_Float16)v[0]; o[1]=(_Float16)v[1]; o[2]=(_Float16)v[2]; o[3]=(_Float16)v[3];
      ((f16x4*)(Wi16 + (size_t)row * kDM))[cv] = o;
    } else if (i < kCvtX + kCvtW + kCvtO) {
      i -= kCvtX + kCvtW;
      const f4 v = ((const f4*)W_out)[i];
      f16x4 o; o[0]=(_Float16)v[0]; o[1]=(_Float16)v[1]; o[2]=(_Float16)v[2]; o[3]=(_Float16)v[3];
      ((f16x4*)Wo16)[i] = o;
    }
  } else if (bid < kCvtBlocks + kDtBlocks) {
    const int w  = tid >> 6;
    const int l  = tid & 63;
    const int gm = (bid - kCvtBlocks) * 4 + w;
    const float* xr = x + (size_t)gm * kDM;
    float p[32];
#pragma unroll
    for (int h = 0; h < 32; ++h) p[h] = 0.f;
    for (int k0 = 0; k0 < kDM; k0 += 64) {
      const float xv = xr[k0 + l];
#pragma unroll
      for (int h = 0; h < 32; ++h)
        p[h] += xv * W_in[(size_t)(4096 + h * 129 + 128) * kDM + k0 + l];
    }
#pragma unroll
    for (int h = 0; h < 32; ++h) {
      float v = p[h];
      v += __shfl_xor(v, 1);  v += __shfl_xor(v, 2);  v += __shfl_xor(v, 4);
      v += __shfl_xor(v, 8);  v += __shfl_xor(v, 16); v += __shfl_xor(v, 32);
      if (l == 0) {
        const float dtp = v + dt_bias[h];
        const float dt  = (dtp > 20.f) ? dtp : log1pf(__expf(dtp));
        dtb[(size_t)((gm >> 10) * 32 + h) * kL + (gm & 1023)] = dt;
      }
    }
  } else {
    const int i = (bid - kCvtBlocks - kDtBlocks) * 256 + tid;
    if (i < 2048) negA[i] = -__expf(A_log[i]);
  }
}

// ---------------------------------------------------------------------------
// K2: f16 GEMM 128x128, BK=32, f16 out. proj16 = x16 @ Wi16^T
// ---------------------------------------------------------------------------
__global__ __launch_bounds__(256) void gemm1(
    const _Float16* __restrict__ A, const _Float16* __restrict__ Bm,
    _Float16* __restrict__ C, int M, int N, int K) {
  __shared__ alignas(16) _Float16 As[128][32];
  __shared__ alignas(16) _Float16 Bs[128][32];
  const int tid  = threadIdx.x;
  const int lane = tid & 63;
  const int w    = tid >> 6;
  const int m0   = blockIdx.x * 128;
  const int n0   = blockIdx.y * 128;
  const int ra   = lane >> 2;
  const int cc   = (lane & 3) * 8;
  const int wm   = (w & 1) * 64;
  const int wn   = (w >> 1) * 64;
  const int l16  = lane & 15;
  const int l4   = lane >> 4;

  f4 acc[4][4] = {};

  for (int k0 = 0; k0 < K; k0 += 32) {
#pragma unroll
    for (int q = 0; q < 2; ++q) {
      const int row = (w * 2 + q) * 16 + ra;
      async_ld16(A + (size_t)(m0 + row) * K + (k0 + cc), &As[row][cc]);
      int gn = n0 + row;
      gn = gn < N ? gn : N - 1;
      async_ld16(Bm + (size_t)gn * K + (k0 + cc), &Bs[row][cc]);
    }
    __syncthreads();
    f16x8 af[4], bf[4];
#pragma unroll
    for (int t = 0; t < 4; ++t) {
      af[t] = *reinterpret_cast<const f16x8*>(&As[wm + t * 16 + l16][l4 * 8]);
      bf[t] = *reinterpret_cast<const f16x8*>(&Bs[wn + t * 16 + l16][l4 * 8]);
    }
#pragma unroll
    for (int i = 0; i < 4; ++i)
#pragma unroll
      for (int j = 0; j < 4; ++j)
        acc[i][j] = __builtin_amdgcn_mfma_f32_16x16x32_f16(af[i], bf[j], acc[i][j], 0, 0, 0);
    __syncthreads();
  }

  const int col = l16;
  const int r0  = l4 * 4;
#pragma unroll
  for (int i = 0; i < 4; ++i)
#pragma unroll
    for (int j = 0; j < 4; ++j) {
      const int gn = n0 + wn + j * 16 + col;
      if (gn >= N) continue;
#pragma unroll
      for (int r = 0; r < 4; ++r) {
        const int gm = m0 + wm + i * 16 + r0 + r;
        C[(size_t)gm * N + gn] = (_Float16)acc[i][j][r];
      }
    }
}

// ---------------------------------------------------------------------------
// K3: scan pass 1. LDS: Ad f32 (exp at stage), Bd16 raw f16 (async copy),
// Xd16 f16 (conv+SiLU at stage). dt folded in-loop: h = a*h + b*(dt*x).
// lane = d, wave w owns s in [16w,16w+16).
// ---------------------------------------------------------------------------
__global__ __launch_bounds__(256) void scan_pass1(
    const _Float16* __restrict__ proj16, const float* __restrict__ dtb,
    const float* __restrict__ negA, const float* __restrict__ conv_w,
    const float* __restrict__ conv_b, float* __restrict__ hloc,
    float* __restrict__ sdt) {
  __shared__ alignas(16) float Ad[kQ][64];       // 16 KB
  __shared__ alignas(16) _Float16 Bd[kQ][64];    // 8 KB
  __shared__ alignas(16) _Float16 Xd[kQ][64];    // 8 KB
  __shared__ float dts[kQ];
  const int tid  = threadIdx.x;
  const int bn   = blockIdx.x >> 4;
  const int c    = blockIdx.x & (kNC - 1);
  const int lane = tid & 63;
  const int w    = tid >> 6;
  const int b    = bn >> 5, n = bn & 31;
  const int l0   = c * kQ;

  // raw B copy: 64 rows x 128B
#pragma unroll
  for (int i = 0; i < 2; ++i) {
    const int row = i * 32 + (tid >> 3);
    const int ch  = (tid & 7) * 8;
    async_ld16(proj16 + (size_t)(b * kL + l0 + row) * kDPROJ + 4096 + n * 64 + ch,
               &Bd[row][ch]);
  }
  // staged compute: thread = (l = tid>>2, q4 = (tid&3)*16)
  {
    const int l  = tid >> 2;
    const int q4 = (tid & 3) * 16;
    const int gl = l0 + l;
    const float dtl = dtb[(size_t)bn * kL + gl];
    if ((tid & 3) == 0) dts[l] = dtl;
#pragma unroll
    for (int j = 0; j < 16; ++j)
      Ad[l][q4 + j] = __expf(negA[n * 64 + q4 + j] * dtl);
    float acc[16];
#pragma unroll
    for (int j = 0; j < 16; ++j) acc[j] = conv_b[n * 64 + q4 + j];
#pragma unroll
    for (int jj = 0; jj < 4; ++jj) {
      const int r = gl - 3 + jj;
      if (r < 0) continue;
      const _Float16* pX = proj16 + (size_t)(b * kL + r) * kDPROJ + n * 64 + q4;
      const f16x8 v0 = *(const f16x8*)pX;
      const f16x8 v1 = *(const f16x8*)(pX + 8);
#pragma unroll
      for (int j = 0; j < 8; ++j) {
        acc[j]     += conv_w[(n * 64 + q4 + j) * 4 + jj]     * (float)v0[j];
        acc[8 + j] += conv_w[(n * 64 + q4 + 8 + j) * 4 + jj] * (float)v1[j];
      }
    }
    f16x8 o0, o1;
#pragma unroll
    for (int j = 0; j < 8; ++j) {
      const float a0 = acc[j], a1 = acc[8 + j];
      o0[j] = (_Float16)(a0 / (1.f + __expf(-a0)));
      o1[j] = (_Float16)(a1 / (1.f + __expf(-a1)));
    }
    *(f16x8*)&Xd[l][q4]     = o0;
    *(f16x8*)&Xd[l][q4 + 8] = o1;
  }
  __syncthreads();

  if (tid == 0) {
    float s = 0.f;
    for (int t = 0; t < kQ; ++t) s += dts[t];
    sdt[bn * kNC + c] = s;
  }

  float h[16];
#pragma unroll
  for (int j = 0; j < 16; ++j) h[j] = 0.f;

#pragma unroll 4
  for (int t = 0; t < kQ; ++t) {
    f4 a[4];
#pragma unroll
    for (int j = 0; j < 4; ++j) a[j] = ((const f4*)&Ad[t][w * 16])[j];
    const f16x8 b0 = *(const f16x8*)&Bd[t][w * 16];
    const f16x8 b1 = *(const f16x8*)&Bd[t][w * 16 + 8];
    const float xtp = (float)Xd[t][lane] * dts[t];
#pragma unroll
    for (int q = 0; q < 4; ++q)
#pragma unroll
      for (int j = 0; j < 4; ++j) {
        const int sj = q * 4 + j;
        const float bv = (float)(sj < 8 ? b0[sj & 7] : b1[sj & 7]);
        h[sj] = fmaf(a[q][j], h[sj], bv * xtp);
      }
  }

  float* hp = hloc + (((size_t)bn * kNC + c) * 64 + w * 16) * 64 + lane;
#pragma unroll
  for (int j = 0; j < 16; ++j) hp[(size_t)j * 64] = h[j];
}

// ---------------------------------------------------------------------------
// K4: chunk stitching. h_in[c+1] = exp(negA_s * sdt[c]) * h_in[c] + hloc[c]
// ---------------------------------------------------------------------------
__global__ __launch_bounds__(256) void scan_pass2(
    const float* __restrict__ hloc, const float* __restrict__ sdt,
    const float* __restrict__ negA, float* __restrict__ hin) {
  const int bn = blockIdx.x >> 2;
  const int dq = blockIdx.x & 3;
  const int n  = bn & 31;
  const int s  = threadIdx.x >> 2;
  const int d0 = dq * 16 + (threadIdx.x & 3) * 4;
  const float Aa = negA[n * 64 + s];
  f4 h = {};
  for (int c = 0; c < kNC; ++c) {
    const size_t off = (((size_t)bn * kNC + c) * 64 + s) * 64 + d0;
    const float ap = __expf(Aa * sdt[bn * kNC + c]);
    *(f4*)(hin + off) = h;
    h = ap * h + *(const f4*)(hloc + off);
  }
}

// ---------------------------------------------------------------------------
// K5: scan pass 3. LDS: Ad f32, Bd/Cd/Zd raw f16 (async copies), Xd16 f16.
// dt folded in-loop; silu(z) at write time. lane=(sg,dd), d = w*16+dd.
// ---------------------------------------------------------------------------
__global__ __launch_bounds__(256) void scan_pass3(
    const _Float16* __restrict__ proj16, const float* __restrict__ dtb,
    const float* __restrict__ negA, const float* __restrict__ conv_w,
    const float* __restrict__ conv_b, const float* __restrict__ hin,
    const float* __restrict__ Dv, _Float16* __restrict__ yin) {
  __shared__ alignas(16) float Ad[kQ][64];       // 16 KB
  __shared__ alignas(16) _Float16 Bd[kQ][64];    // 8 KB
  __shared__ alignas(16) _Float16 Cd[kQ][64];    // 8 KB
  __shared__ alignas(16) _Float16 Xd[kQ][64];    // 8 KB
  __shared__ alignas(16) _Float16 Zd[kQ][64];    // 8 KB
  __shared__ float dts[kQ];
  const int tid  = threadIdx.x;
  const int bn   = blockIdx.x >> 4;
  const int c    = blockIdx.x & (kNC - 1);
  const int lane = tid & 63;
  const int w    = tid >> 6;
  const int sg   = lane >> 4;
  const int dd   = lane & 15;
  const int b    = bn >> 5, n = bn & 31;
  const int l0   = c * kQ;
  const int d    = w * 16 + dd;

  // raw copies: B, C, Z (64 rows x 128B each)
#pragma unroll
  for (int i = 0; i < 2; ++i) {
    const int row = i * 32 + (tid >> 3);
    const int ch  = (tid & 7) * 8;
    const size_t rb = (size_t)(b * kL + l0 + row) * kDPROJ + n * 64 + ch;
    async_ld16(proj16 + rb + 4096, &Bd[row][ch]);
    async_ld16(proj16 + rb + 6144, &Cd[row][ch]);
    async_ld16(proj16 + rb + 2048, &Zd[row][ch]);
  }
  // staged compute: Ad + conv/SiLU Xd
  {
    const int l  = tid >> 2;
    const int q4 = (tid & 3) * 16;
    const int gl = l0 + l;
    const float dtl = dtb[(size_t)bn * kL + gl];
    if ((tid & 3) == 0) dts[l] = dtl;
#pragma unroll
    for (int j = 0; j < 16; ++j)
      Ad[l][q4 + j] = __expf(negA[n * 64 + q4 + j] * dtl);
    float acc[16];
#pragma unroll
    for (int j = 0; j < 16; ++j) acc[j] = conv_b[n * 64 + q4 + j];
#pragma unroll
    for (int jj = 0; jj < 4; ++jj) {
      const int r = gl - 3 + jj;
      if (r < 0) continue;
      const _Float16* pX = proj16 + (size_t)(b * kL + r) * kDPROJ + n * 64 + q4;
      const f16x8 v0 = *(const f16x8*)pX;
      const f16x8 v1 = *(const f16x8*)(pX + 8);
#pragma unroll
      for (int j = 0; j < 8; ++j) {
        acc[j]     += conv_w[(n * 64 + q4 + j) * 4 + jj]     * (float)v0[j];
        acc[8 + j] += conv_w[(n * 64 + q4 + 8 + j) * 4 + jj] * (float)v1[j];
      }
    }
    f16x8 o0, o1;
#pragma unroll
    for (int j = 0; j < 8; ++j) {
      const float a0 = acc[j], a1 = acc[8 + j];
      o0[j] = (_Float16)(a0 / (1.f + __expf(-a0)));
      o1[j] = (_Float16)(a1 / (1.f + __expf(-a1)));
    }
    *(f16x8*)&Xd[l][q4]     = o0;
    *(f16x8*)&Xd[l][q4 + 8] = o1;
  }

  // h init (global, overlaps staging)
  float h[16];
  const float* hp = hin + (((size_t)bn * kNC + c) * 64 + sg * 16) * 64 + d;
#pragma unroll
  for (int j = 0; j < 16; ++j) h[j] = hp[(size_t)j * 64];

  const float Dn = Dv[n];
  _Float16* Yb = yin + (size_t)(b * kL + l0) * kDI + n * 64 + d;
  __syncthreads();

#pragma unroll 4
  for (int t = 0; t < kQ; ++t) {
    f4 a[4];
#pragma unroll
    for (int j = 0; j < 4; ++j) a[j] = ((const f4*)&Ad[t][sg * 16])[j];
    const f16x8 b0 = *(const f16x8*)&Bd[t][sg * 16];
    const f16x8 b1 = *(const f16x8*)&Bd[t][sg * 16 + 8];
    const f16x8 c0 = *(const f16x8*)&Cd[t][sg * 16];
    const f16x8 c1 = *(const f16x8*)&Cd[t][sg * 16 + 8];
    const float xt  = (float)Xd[t][d];
    const float xtp = xt * dts[t];

    float pq[4];
#pragma unroll
    for (int q = 0; q < 4; ++q) {
      float p = 0.f;
#pragma unroll
      for (int j = 0; j < 4; ++j) {
        const int sj = q * 4 + j;
        const float bv = (float)(sj < 8 ? b0[sj & 7] : b1[sj & 7]);
        const float cv = (float)(sj < 8 ? c0[sj & 7] : c1[sj & 7]);
        h[sj] = fmaf(a[q][j], h[sj], bv * xtp);
        p = fmaf(cv, h[sj], p);
      }
      pq[q] = p;
    }
    float p = (pq[0] + pq[1]) + (pq[2] + pq[3]);
    p += __shfl_xor(p, 16);
    p += __shfl_xor(p, 32);
    if (sg == 0) {
      const float z = (float)Zd[t][d];
      const float zs = z / (1.f + __expf(-z));
      Yb[(size_t)t * kDI] = (_Float16)((p + Dn * xt) * zs);
    }
  }
}

// ---------------------------------------------------------------------------
// K6: out[2048,1024] f32 = yin @ Wo16^T. 64x64 tile, BK=32, 512 blocks.
// ---------------------------------------------------------------------------
__global__ __launch_bounds__(256) void gemm_out(
    const _Float16* __restrict__ A, const _Float16* __restrict__ Bm,
    float* __restrict__ C) {
  __shared__ alignas(16) _Float16 As[64][32];
  __shared__ alignas(16) _Float16 Bs[64][32];
  const int tid  = threadIdx.x;
  const int lane = tid & 63;
  const int w    = tid >> 6;
  const int m0   = blockIdx.x * 64;
  const int n0   = blockIdx.y * 64;
  const int row  = tid >> 2;          // 0..63 staging row
  const int cc   = (tid & 3) * 8;
  const int wm   = (w & 1) * 32;
  const int wn   = (w >> 1) * 32;
  const int l16  = lane & 15;
  const int l4   = lane >> 4;

  f4 acc[2][2] = {};

  for (int k0 = 0; k0 < kDI; k0 += 32) {
    async_ld16(A + (size_t)(m0 + row) * kDI + (k0 + cc), &As[row][cc]);
    async_ld16(Bm + (size_t)(n0 + row) * kDI + (k0 + cc), &Bs[row][cc]);
    __syncthreads();
    f16x8 af[2], bf[2];
#pragma unroll
    for (int t = 0; t < 2; ++t) {
      af[t] = *reinterpret_cast<const f16x8*>(&As[wm + t * 16 + l16][l4 * 8]);
      bf[t] = *reinterpret_cast<const f16x8*>(&Bs[wn + t * 16 + l16][l4 * 8]);
    }
#pragma unroll
    for (int i = 0; i < 2; ++i)
#pragma unroll
      for (int j = 0; j < 2; ++j)
        acc[i][j] = __builtin_amdgcn_mfma_f32_16x16x32_f16(af[i], bf[j], acc[i][j], 0, 0, 0);
    __syncthreads();
  }

  const int col = l16;
  const int r0  = l4 * 4;
#pragma unroll
  for (int i = 0; i < 2; ++i)
#pragma unroll
    for (int j = 0; j < 2; ++j) {
      const int gn = n0 + wn + j * 16 + col;
#pragma unroll
      for (int r = 0; r < 4; ++r) {
        const int gm = m0 + wm + i * 16 + r0 + r;
        C[(size_t)gm * kDM + gn] = acc[i][j][r];
      }
    }
}

// ---------------------------------------------------------------------------
extern "C" void kernel_launch(void* const* d_in, const int* in_sizes, int n_in,
                              void* d_out, int out_size, void* d_ws, size_t ws_size,
                              hipStream_t stream) {
  const float* x      = (const float*)d_in[0];
  const float* W_in   = (const float*)d_in[1];
  const float* conv_w = (const float*)d_in[2];
  const float* conv_b = (const float*)d_in[3];
  const float* A_log  = (const float*)d_in[4];
  const float* Dv     = (const float*)d_in[5];
  const float* dt_b   = (const float*)d_in[6];
  const float* W_out  = (const float*)d_in[7];
  float* out = (float*)d_out;

  char* p = (char*)d_ws;
  _Float16* proj16 = (_Float16*)p; p += (size_t)kBL * kDPROJ * 2;   // 33.7 MB
  float* dtb   = (float*)p; p += (size_t)64 * kL * 4;
  float* negA  = (float*)p; p += 2048 * 4;
  float* sdt   = (float*)p; p += 64 * kNC * 4 + 4032;
  float* hloc  = (float*)p; p += (size_t)64 * kNC * 64 * 64 * 4;    // 16.8 MB
  float* hin   = (float*)p; p += (size_t)64 * kNC * 64 * 64 * 4;    // 16.8 MB
  _Float16* yin  = (_Float16*)p; p += (size_t)kBL * kDI * 2;        // 8.4 MB
  _Float16* Wo16 = (_Float16*)p; p += (size_t)kDM * kDI * 2;        // 4.2 MB
  _Float16* x16  = (_Float16*)hloc;                 // alias (pre-scan phase)
  _Float16* Wi16 = x16 + (size_t)kBL * kDM;

  prep_inputs<<<kCvtBlocks + kDtBlocks + kNegABlocks, 256, 0, stream>>>(
      x, W_in, W_out, A_log, dt_b, x16, Wi16, Wo16, dtb, negA);

  gemm1<<<dim3(kBL / 128, (kDPROJ + 127) / 128), 256, 0, stream>>>(
      x16, Wi16, proj16, kBL, kDPROJ, kDM);

  scan_pass1<<<64 * kNC, 256, 0, stream>>>(proj16, dtb, negA, conv_w, conv_b, hloc, sdt);
  scan_pass2<<<256, 256, 0, stream>>>(hloc, sdt, negA, hin);
  scan_pass3<<<64 * kNC, 256, 0, stream>>>(proj16, dtb, negA, conv_w, conv_b, hin, Dv, yin);

  gemm_out<<<dim3(kBL / 64, kDM / 64), 256, 0, stream>>>(yin, Wo16, out);
}

// Round 8
// 331.144 us; speedup vs baseline: 1.0075x; 1.0075x over previous
//
#include <hip/hip_runtime.h>
#include <hip/hip_fp16.h>

namespace {
constexpr int kB  = 2;
constexpr int kL  = 1024;
constexpr int kDM = 1024;
constexpr int kDI = 2048;
constexpr int kPROJW = 8192;   // proj16 row: [x 0..2048 | z ..4096 | B ..6144 | C ..8192]
constexpr int kBL = 2048;
constexpr int kQ  = 64;
constexpr int kNC = 16;
constexpr int kCvtX = kBL * kDM / 4;      // 524288 vec4
constexpr int kCvtW = kPROJW * kDM / 4;   // 2097152
constexpr int kCvtO = kDM * kDI / 4;      // 524288
constexpr int kCvtBlocks  = (kCvtX + kCvtW + kCvtO) / 256;  // 12288
constexpr int kDtBlocks   = 512;
constexpr int kNegABlocks = 8;
}

typedef float f4 __attribute__((ext_vector_type(4)));
typedef _Float16 f16x8 __attribute__((ext_vector_type(8)));
typedef _Float16 f16x4 __attribute__((ext_vector_type(4)));

__device__ __forceinline__ void async_ld16(const void* g, void* l) {
  __builtin_amdgcn_global_load_lds(
      (const __attribute__((address_space(1))) void*)g,
      (__attribute__((address_space(3))) void*)l, 16, 0, 0);
}

// ---------------------------------------------------------------------------
// K1: f32->f16 cvt of x / W_in(row-permuted, dt rows dropped) / W_out
//     + f32 dt-GEMM (dtb = softplus(x @ Wdt^T + bias)) + negA.
// ---------------------------------------------------------------------------
__global__ __launch_bounds__(256) void prep_inputs(
    const float* __restrict__ x, const float* __restrict__ W_in,
    const float* __restrict__ W_out, const float* __restrict__ A_log,
    const float* __restrict__ dt_bias, _Float16* __restrict__ x16,
    _Float16* __restrict__ Wi16, _Float16* __restrict__ Wo16,
    float* __restrict__ dtb, float* __restrict__ negA) {
  const int bid = blockIdx.x;
  const int tid = threadIdx.x;
  if (bid < kCvtBlocks) {
    int i = bid * 256 + tid;
    if (i < kCvtX) {
      const f4 v = ((const f4*)x)[i];
      f16x4 o; o[0]=(_Float16)v[0]; o[1]=(_Float16)v[1]; o[2]=(_Float16)v[2]; o[3]=(_Float16)v[3];
      ((f16x4*)x16)[i] = o;
    } else if (i < kCvtX + kCvtW) {
      i -= kCvtX;
      const int row = i >> 8;        // 256 vec4 per 1024-col row; row in [0,8192)
      const int cv  = i & 255;
      int srow;
      if (row < 4096)      srow = row;
      else if (row < 6144) { const int m = row - 4096; srow = 4096 + (m >> 6) * 129 + (m & 63); }
      else                 { const int m = row - 6144; srow = 4096 + (m >> 6) * 129 + 64 + (m & 63); }
      const f4 v = ((const f4*)(W_in + (size_t)srow * kDM))[cv];
      f16x4 o; o[0]=(_Float16)v[0]; o[1]=(_Float16)v[1]; o[2]=(_Float16)v[2]; o[3]=(_Float16)v[3];
      ((f16x4*)(Wi16 + (size_t)row * kDM))[cv] = o;
    } else {
      i -= kCvtX + kCvtW;
      const f4 v = ((const f4*)W_out)[i];
      f16x4 o; o[0]=(_Float16)v[0]; o[1]=(_Float16)v[1]; o[2]=(_Float16)v[2]; o[3]=(_Float16)v[3];
      ((f16x4*)Wo16)[i] = o;
    }
  } else if (bid < kCvtBlocks + kDtBlocks) {
    const int w  = tid >> 6;
    const int l  = tid & 63;
    const int gm = (bid - kCvtBlocks) * 4 + w;
    const float* xr = x + (size_t)gm * kDM;
    float p[32];
#pragma unroll
    for (int h = 0; h < 32; ++h) p[h] = 0.f;
    for (int k0 = 0; k0 < kDM; k0 += 64) {
      const float xv = xr[k0 + l];
#pragma unroll
      for (int h = 0; h < 32; ++h)
        p[h] += xv * W_in[(size_t)(4096 + h * 129 + 128) * kDM + k0 + l];
    }
#pragma unroll
    for (int h = 0; h < 32; ++h) {
      float v = p[h];
      v += __shfl_xor(v, 1);  v += __shfl_xor(v, 2);  v += __shfl_xor(v, 4);
      v += __shfl_xor(v, 8);  v += __shfl_xor(v, 16); v += __shfl_xor(v, 32);
      if (l == 0) {
        const float dtp = v + dt_bias[h];
        const float dt  = (dtp > 20.f) ? dtp : log1pf(__expf(dtp));
        dtb[(size_t)((gm >> 10) * 32 + h) * kL + (gm & 1023)] = dt;
      }
    }
  } else {
    const int i = (bid - kCvtBlocks - kDtBlocks) * 256 + tid;
    if (i < 2048) negA[i] = -__expf(A_log[i]);
  }
}

// ---------------------------------------------------------------------------
// K2: f16 GEMM 128x128, BK=32, f16 out. proj16[2048,8192] = x16 @ Wi16^T.
// N = 8192 (64 exact tiles, no clamp needed).
// ---------------------------------------------------------------------------
__global__ __launch_bounds__(256) void gemm1(
    const _Float16* __restrict__ A, const _Float16* __restrict__ Bm,
    _Float16* __restrict__ C, int M, int N, int K) {
  __shared__ alignas(16) _Float16 As[128][32];
  __shared__ alignas(16) _Float16 Bs[128][32];
  const int tid  = threadIdx.x;
  const int lane = tid & 63;
  const int w    = tid >> 6;
  const int m0   = blockIdx.x * 128;
  const int n0   = blockIdx.y * 128;
  const int ra   = lane >> 2;
  const int cc   = (lane & 3) * 8;
  const int wm   = (w & 1) * 64;
  const int wn   = (w >> 1) * 64;
  const int l16  = lane & 15;
  const int l4   = lane >> 4;

  f4 acc[4][4] = {};

  for (int k0 = 0; k0 < K; k0 += 32) {
#pragma unroll
    for (int q = 0; q < 2; ++q) {
      const int row = (w * 2 + q) * 16 + ra;
      async_ld16(A + (size_t)(m0 + row) * K + (k0 + cc), &As[row][cc]);
      async_ld16(Bm + (size_t)(n0 + row) * K + (k0 + cc), &Bs[row][cc]);
    }
    __syncthreads();
    f16x8 af[4], bf[4];
#pragma unroll
    for (int t = 0; t < 4; ++t) {
      af[t] = *reinterpret_cast<const f16x8*>(&As[wm + t * 16 + l16][l4 * 8]);
      bf[t] = *reinterpret_cast<const f16x8*>(&Bs[wn + t * 16 + l16][l4 * 8]);
    }
#pragma unroll
    for (int i = 0; i < 4; ++i)
#pragma unroll
      for (int j = 0; j < 4; ++j)
        acc[i][j] = __builtin_amdgcn_mfma_f32_16x16x32_f16(af[i], bf[j], acc[i][j], 0, 0, 0);
    __syncthreads();
  }

  const int col = l16;      // C/D: col = lane&15, row = (lane>>4)*4 + reg
  const int r0  = l4 * 4;
#pragma unroll
  for (int i = 0; i < 4; ++i)
#pragma unroll
    for (int j = 0; j < 4; ++j) {
      const int gn = n0 + wn + j * 16 + col;
#pragma unroll
      for (int r = 0; r < 4; ++r) {
        const int gm = m0 + wm + i * 16 + r0 + r;
        C[(size_t)gm * N + gn] = (_Float16)acc[i][j][r];
      }
    }
}

// ---------------------------------------------------------------------------
// K3: scan pass 1. LDS: Ad f32 (exp at stage), Bd raw f16 (async copy),
// Xd = f16(silu(conv(x)) * dt) (dt pre-folded). In-loop fma_mix patterns.
// lane = d, wave w owns s in [16w,16w+16).
// ---------------------------------------------------------------------------
__global__ __launch_bounds__(256) void scan_pass1(
    const _Float16* __restrict__ proj16, const float* __restrict__ dtb,
    const float* __restrict__ negA, const float* __restrict__ conv_w,
    const float* __restrict__ conv_b, float* __restrict__ hloc,
    float* __restrict__ sdt) {
  __shared__ alignas(16) float Ad[kQ][64];       // 16 KB
  __shared__ alignas(16) _Float16 Bd[kQ][64];    // 8 KB
  __shared__ alignas(16) _Float16 Xd[kQ][64];    // 8 KB
  __shared__ float dts[kQ];
  const int tid  = threadIdx.x;
  const int bn   = blockIdx.x >> 4;
  const int c    = blockIdx.x & (kNC - 1);
  const int lane = tid & 63;
  const int w    = tid >> 6;
  const int b    = bn >> 5, n = bn & 31;
  const int l0   = c * kQ;

  // raw B copy: 64 rows x 128B
#pragma unroll
  for (int i = 0; i < 2; ++i) {
    const int row = i * 32 + (tid >> 3);
    const int ch  = (tid & 7) * 8;
    async_ld16(proj16 + (size_t)(b * kL + l0 + row) * kPROJW + 4096 + n * 64 + ch,
               &Bd[row][ch]);
  }
  // staged compute: thread = (l = tid>>2, q4 = (tid&3)*16)
  {
    const int l  = tid >> 2;
    const int q4 = (tid & 3) * 16;
    const int gl = l0 + l;
    const float dtl = dtb[(size_t)bn * kL + gl];
    if ((tid & 3) == 0) dts[l] = dtl;
#pragma unroll
    for (int j = 0; j < 16; ++j)
      Ad[l][q4 + j] = __expf(negA[n * 64 + q4 + j] * dtl);
    float acc[16];
#pragma unroll
    for (int j = 0; j < 16; ++j) acc[j] = conv_b[n * 64 + q4 + j];
#pragma unroll
    for (int jj = 0; jj < 4; ++jj) {
      const int r = gl - 3 + jj;
      if (r < 0) continue;
      const _Float16* pX = proj16 + (size_t)(b * kL + r) * kPROJW + n * 64 + q4;
      const f16x8 v0 = *(const f16x8*)pX;
      const f16x8 v1 = *(const f16x8*)(pX + 8);
#pragma unroll
      for (int j = 0; j < 8; ++j) {
        acc[j]     += conv_w[(n * 64 + q4 + j) * 4 + jj]     * (float)v0[j];
        acc[8 + j] += conv_w[(n * 64 + q4 + 8 + j) * 4 + jj] * (float)v1[j];
      }
    }
    f16x8 o0, o1;
#pragma unroll
    for (int j = 0; j < 8; ++j) {
      const float a0 = acc[j], a1 = acc[8 + j];
      o0[j] = (_Float16)(dtl * a0 / (1.f + __expf(-a0)));
      o1[j] = (_Float16)(dtl * a1 / (1.f + __expf(-a1)));
    }
    *(f16x8*)&Xd[l][q4]     = o0;
    *(f16x8*)&Xd[l][q4 + 8] = o1;
  }
  __syncthreads();

  if (tid == 0) {
    float s = 0.f;
    for (int t = 0; t < kQ; ++t) s += dts[t];
    sdt[bn * kNC + c] = s;
  }

  float h[16];
#pragma unroll
  for (int j = 0; j < 16; ++j) h[j] = 0.f;

#pragma unroll 4
  for (int t = 0; t < kQ; ++t) {
    f4 a[4];
#pragma unroll
    for (int j = 0; j < 4; ++j) a[j] = ((const f4*)&Ad[t][w * 16])[j];
    const f16x8 b0 = *(const f16x8*)&Bd[t][w * 16];
    const f16x8 b1 = *(const f16x8*)&Bd[t][w * 16 + 8];
    const float xdt = (float)Xd[t][lane];
#pragma unroll
    for (int q = 0; q < 4; ++q)
#pragma unroll
      for (int j = 0; j < 4; ++j) {
        const int sj = q * 4 + j;
        // bx via v_fma_mix (f16 src folded), h via v_fmac_f32
        const float bx = fmaf((float)(sj < 8 ? b0[sj & 7] : b1[sj & 7]), xdt, 0.f);
        h[sj] = fmaf(a[q][j], h[sj], bx);
      }
  }

  float* hp = hloc + (((size_t)bn * kNC + c) * 64 + w * 16) * 64 + lane;
#pragma unroll
  for (int j = 0; j < 16; ++j) hp[(size_t)j * 64] = h[j];
}

// ---------------------------------------------------------------------------
// K4: chunk stitching. h_in[c+1] = exp(negA_s * sdt[c]) * h_in[c] + hloc[c]
// ---------------------------------------------------------------------------
__global__ __launch_bounds__(256) void scan_pass2(
    const float* __restrict__ hloc, const float* __restrict__ sdt,
    const float* __restrict__ negA, float* __restrict__ hin) {
  const int bn = blockIdx.x >> 2;
  const int dq = blockIdx.x & 3;
  const int n  = bn & 31;
  const int s  = threadIdx.x >> 2;
  const int d0 = dq * 16 + (threadIdx.x & 3) * 4;
  const float Aa = negA[n * 64 + s];
  f4 h = {};
  for (int c = 0; c < kNC; ++c) {
    const size_t off = (((size_t)bn * kNC + c) * 64 + s) * 64 + d0;
    const float ap = __expf(Aa * sdt[bn * kNC + c]);
    *(f4*)(hin + off) = h;
    h = ap * h + *(const f4*)(hloc + off);
  }
}

// ---------------------------------------------------------------------------
// K5: scan pass 3. LDS: Ad f32, Bd/Cd/Zd raw f16, Xd = f16(x_silu * dt),
// rdt[] = 1/dt for epilogue x recovery. In-loop fma_mix; h f32.
// lane=(sg,dd), d = w*16+dd.
// ---------------------------------------------------------------------------
__global__ __launch_bounds__(256) void scan_pass3(
    const _Float16* __restrict__ proj16, const float* __restrict__ dtb,
    const float* __restrict__ negA, const float* __restrict__ conv_w,
    const float* __restrict__ conv_b, const float* __restrict__ hin,
    const float* __restrict__ Dv, _Float16* __restrict__ yin) {
  __shared__ alignas(16) float Ad[kQ][64];       // 16 KB
  __shared__ alignas(16) _Float16 Bd[kQ][64];    // 8 KB
  __shared__ alignas(16) _Float16 Cd[kQ][64];    // 8 KB
  __shared__ alignas(16) _Float16 Xd[kQ][64];    // 8 KB
  __shared__ alignas(16) _Float16 Zd[kQ][64];    // 8 KB
  __shared__ float rdt[kQ];
  const int tid  = threadIdx.x;
  const int bn   = blockIdx.x >> 4;
  const int c    = blockIdx.x & (kNC - 1);
  const int lane = tid & 63;
  const int w    = tid >> 6;
  const int sg   = lane >> 4;
  const int dd   = lane & 15;
  const int b    = bn >> 5, n = bn & 31;
  const int l0   = c * kQ;
  const int d    = w * 16 + dd;

  // raw copies: B, C, Z (64 rows x 128B each)
#pragma unroll
  for (int i = 0; i < 2; ++i) {
    const int row = i * 32 + (tid >> 3);
    const int ch  = (tid & 7) * 8;
    const size_t rb = (size_t)(b * kL + l0 + row) * kPROJW + n * 64 + ch;
    async_ld16(proj16 + rb + 4096, &Bd[row][ch]);
    async_ld16(proj16 + rb + 6144, &Cd[row][ch]);
    async_ld16(proj16 + rb + 2048, &Zd[row][ch]);
  }
  // staged compute: Ad + conv/SiLU Xd (dt-folded)
  {
    const int l  = tid >> 2;
    const int q4 = (tid & 3) * 16;
    const int gl = l0 + l;
    const float dtl = dtb[(size_t)bn * kL + gl];
    if ((tid & 3) == 0) rdt[l] = 1.0f / dtl;
#pragma unroll
    for (int j = 0; j < 16; ++j)
      Ad[l][q4 + j] = __expf(negA[n * 64 + q4 + j] * dtl);
    float acc[16];
#pragma unroll
    for (int j = 0; j < 16; ++j) acc[j] = conv_b[n * 64 + q4 + j];
#pragma unroll
    for (int jj = 0; jj < 4; ++jj) {
      const int r = gl - 3 + jj;
      if (r < 0) continue;
      const _Float16* pX = proj16 + (size_t)(b * kL + r) * kPROJW + n * 64 + q4;
      const f16x8 v0 = *(const f16x8*)pX;
      const f16x8 v1 = *(const f16x8*)(pX + 8);
#pragma unroll
      for (int j = 0; j < 8; ++j) {
        acc[j]     += conv_w[(n * 64 + q4 + j) * 4 + jj]     * (float)v0[j];
        acc[8 + j] += conv_w[(n * 64 + q4 + 8 + j) * 4 + jj] * (float)v1[j];
      }
    }
    f16x8 o0, o1;
#pragma unroll
    for (int j = 0; j < 8; ++j) {
      const float a0 = acc[j], a1 = acc[8 + j];
      o0[j] = (_Float16)(dtl * a0 / (1.f + __expf(-a0)));
      o1[j] = (_Float16)(dtl * a1 / (1.f + __expf(-a1)));
    }
    *(f16x8*)&Xd[l][q4]     = o0;
    *(f16x8*)&Xd[l][q4 + 8] = o1;
  }

  // h init (global, overlaps staging)
  float h[16];
  const float* hp = hin + (((size_t)bn * kNC + c) * 64 + sg * 16) * 64 + d;
#pragma unroll
  for (int j = 0; j < 16; ++j) h[j] = hp[(size_t)j * 64];

  const float Dn = Dv[n];
  _Float16* Yb = yin + (size_t)(b * kL + l0) * kDI + n * 64 + d;
  __syncthreads();

#pragma unroll 4
  for (int t = 0; t < kQ; ++t) {
    f4 a[4];
#pragma unroll
    for (int j = 0; j < 4; ++j) a[j] = ((const f4*)&Ad[t][sg * 16])[j];
    const f16x8 b0 = *(const f16x8*)&Bd[t][sg * 16];
    const f16x8 b1 = *(const f16x8*)&Bd[t][sg * 16 + 8];
    const f16x8 c0 = *(const f16x8*)&Cd[t][sg * 16];
    const f16x8 c1 = *(const f16x8*)&Cd[t][sg * 16 + 8];
    const float xdt = (float)Xd[t][d];

    float pq[4];
#pragma unroll
    for (int q = 0; q < 4; ++q) {
      float p = 0.f;
#pragma unroll
      for (int j = 0; j < 4; ++j) {
        const int sj = q * 4 + j;
        const float bx = fmaf((float)(sj < 8 ? b0[sj & 7] : b1[sj & 7]), xdt, 0.f);
        h[sj] = fmaf(a[q][j], h[sj], bx);
        p = fmaf((float)(sj < 8 ? c0[sj & 7] : c1[sj & 7]), h[sj], p);
      }
      pq[q] = p;
    }
    float p = (pq[0] + pq[1]) + (pq[2] + pq[3]);
    p += __shfl_xor(p, 16);
    p += __shfl_xor(p, 32);
    if (sg == 0) {
      const float xt = xdt * rdt[t];             // recover silu(conv(x))
      const float z = (float)Zd[t][d];
      const float zs = z / (1.f + __expf(-z));
      Yb[(size_t)t * kDI] = (_Float16)((p + Dn * xt) * zs);
    }
  }
}

// ---------------------------------------------------------------------------
// K6: out[2048,1024] f32 = yin @ Wo16^T. 64x64 tile, BK=32, 512 blocks.
// ---------------------------------------------------------------------------
__global__ __launch_bounds__(256) void gemm_out(
    const _Float16* __restrict__ A, const _Float16* __restrict__ Bm,
    float* __restrict__ C) {
  __shared__ alignas(16) _Float16 As[64][32];
  __shared__ alignas(16) _Float16 Bs[64][32];
  const int tid  = threadIdx.x;
  const int lane = tid & 63;
  const int w    = tid >> 6;
  const int m0   = blockIdx.x * 64;
  const int n0   = blockIdx.y * 64;
  const int row  = tid >> 2;
  const int cc   = (tid & 3) * 8;
  const int wm   = (w & 1) * 32;
  const int wn   = (w >> 1) * 32;
  const int l16  = lane & 15;
  const int l4   = lane >> 4;

  f4 acc[2][2] = {};

  for (int k0 = 0; k0 < kDI; k0 += 32) {
    async_ld16(A + (size_t)(m0 + row) * kDI + (k0 + cc), &As[row][cc]);
    async_ld16(Bm + (size_t)(n0 + row) * kDI + (k0 + cc), &Bs[row][cc]);
    __syncthreads();
    f16x8 af[2], bf[2];
#pragma unroll
    for (int t = 0; t < 2; ++t) {
      af[t] = *reinterpret_cast<const f16x8*>(&As[wm + t * 16 + l16][l4 * 8]);
      bf[t] = *reinterpret_cast<const f16x8*>(&Bs[wn + t * 16 + l16][l4 * 8]);
    }
#pragma unroll
    for (int i = 0; i < 2; ++i)
#pragma unroll
      for (int j = 0; j < 2; ++j)
        acc[i][j] = __builtin_amdgcn_mfma_f32_16x16x32_f16(af[i], bf[j], acc[i][j], 0, 0, 0);
    __syncthreads();
  }

  const int col = l16;
  const int r0  = l4 * 4;
#pragma unroll
  for (int i = 0; i < 2; ++i)
#pragma unroll
    for (int j = 0; j < 2; ++j) {
      const int gn = n0 + wn + j * 16 + col;
#pragma unroll
      for (int r = 0; r < 4; ++r) {
        const int gm = m0 + wm + i * 16 + r0 + r;
        C[(size_t)gm * kDM + gn] = acc[i][j][r];
      }
    }
}

// ---------------------------------------------------------------------------
extern "C" void kernel_launch(void* const* d_in, const int* in_sizes, int n_in,
                              void* d_out, int out_size, void* d_ws, size_t ws_size,
                              hipStream_t stream) {
  const float* x      = (const float*)d_in[0];
  const float* W_in   = (const float*)d_in[1];
  const float* conv_w = (const float*)d_in[2];
  const float* conv_b = (const float*)d_in[3];
  const float* A_log  = (const float*)d_in[4];
  const float* Dv     = (const float*)d_in[5];
  const float* dt_b   = (const float*)d_in[6];
  const float* W_out  = (const float*)d_in[7];
  float* out = (float*)d_out;

  char* p = (char*)d_ws;
  _Float16* proj16 = (_Float16*)p; p += (size_t)kBL * kPROJW * 2;   // 33.6 MB
  float* dtb   = (float*)p; p += (size_t)64 * kL * 4;
  float* negA  = (float*)p; p += 2048 * 4;
  float* sdt   = (float*)p; p += 64 * kNC * 4 + 4032;
  float* hloc  = (float*)p; p += (size_t)64 * kNC * 64 * 64 * 4;    // 16.8 MB
  float* hin   = (float*)p; p += (size_t)64 * kNC * 64 * 64 * 4;    // 16.8 MB
  _Float16* yin  = (_Float16*)p; p += (size_t)kBL * kDI * 2;        // 8.4 MB
  _Float16* Wo16 = (_Float16*)p; p += (size_t)kDM * kDI * 2;        // 4.2 MB
  _Float16* x16  = (_Float16*)hloc;                 // alias (pre-scan phase)
  _Float16* Wi16 = x16 + (size_t)kBL * kDM;         // 16.8 MB (tail in hin)

  prep_inputs<<<kCvtBlocks + kDtBlocks + kNegABlocks, 256, 0, stream>>>(
      x, W_in, W_out, A_log, dt_b, x16, Wi16, Wo16, dtb, negA);

  gemm1<<<dim3(kBL / 128, kPROJW / 128), 256, 0, stream>>>(
      x16, Wi16, proj16, kBL, kPROJW, kDM);

  scan_pass1<<<64 * kNC, 256, 0, stream>>>(proj16, dtb, negA, conv_w, conv_b, hloc, sdt);
  scan_pass2<<<256, 256, 0, stream>>>(hloc, sdt, negA, hin);
  scan_pass3<<<64 * kNC, 256, 0, stream>>>(proj16, dtb, negA, conv_w, conv_b, hin, Dv, yin);

  gemm_out<<<dim3(kBL / 64, kDM / 64), 256, 0, stream>>>(yin, Wo16, out);
}

// Round 9
// 312.153 us; speedup vs baseline: 1.0687x; 1.0608x over previous
//
#include <hip/hip_runtime.h>
#include <hip/hip_fp16.h>

namespace {
constexpr int kB  = 2;
constexpr int kL  = 1024;
constexpr int kDM = 1024;
constexpr int kDI = 2048;
constexpr int kPROJW = 8192;   // proj16 row: [x 0..2048 | z ..4096 | B ..6144 | C ..8192]
constexpr int kBL = 2048;
constexpr int kQ  = 64;
constexpr int kNC = 16;
constexpr int kCvtX = kBL * kDM / 4;      // 524288 vec4
constexpr int kCvtW = 8224 * kDM / 4;     // 2105344 (8192 cvt rows + 32 dt rows -> WdtT)
constexpr int kCvtO = kDM * kDI / 4;      // 524288
constexpr int kCvtBlocks  = (kCvtX + kCvtW + kCvtO) / 256;  // 12320
constexpr int kNegABlocks = 8;
}

typedef float f4 __attribute__((ext_vector_type(4)));
typedef _Float16 f16x8 __attribute__((ext_vector_type(8)));
typedef _Float16 f16x4 __attribute__((ext_vector_type(4)));

__device__ __forceinline__ void async_ld16(const void* g, void* l) {
  __builtin_amdgcn_global_load_lds(
      (const __attribute__((address_space(1))) void*)g,
      (__attribute__((address_space(3))) void*)l, 16, 0, 0);
}

// ---------------------------------------------------------------------------
// K1: f32->f16 cvt of x / W_in(row-permuted) / W_out + WdtT pack + negA.
// dt rows of W_in go to contiguous f32 WdtT[k][h] (transposed) for dt_gemm.
// ---------------------------------------------------------------------------
__global__ __launch_bounds__(256) void prep_inputs(
    const float* __restrict__ x, const float* __restrict__ W_in,
    const float* __restrict__ W_out, const float* __restrict__ A_log,
    _Float16* __restrict__ x16, _Float16* __restrict__ Wi16,
    _Float16* __restrict__ Wo16, float* __restrict__ WdtT,
    float* __restrict__ negA) {
  const int bid = blockIdx.x;
  const int tid = threadIdx.x;
  if (bid < kCvtBlocks) {
    int i = bid * 256 + tid;
    if (i < kCvtX) {
      const f4 v = ((const f4*)x)[i];
      f16x4 o; o[0]=(_Float16)v[0]; o[1]=(_Float16)v[1]; o[2]=(_Float16)v[2]; o[3]=(_Float16)v[3];
      ((f16x4*)x16)[i] = o;
    } else if (i < kCvtX + kCvtW) {
      i -= kCvtX;
      const int row = i >> 8;        // [0, 8224)
      const int cv  = i & 255;
      if (row < 8192) {
        int srow;
        if (row < 4096)      srow = row;
        else if (row < 6144) { const int m = row - 4096; srow = 4096 + (m >> 6) * 129 + (m & 63); }
        else                 { const int m = row - 6144; srow = 4096 + (m >> 6) * 129 + 64 + (m & 63); }
        const f4 v = ((const f4*)(W_in + (size_t)srow * kDM))[cv];
        f16x4 o; o[0]=(_Float16)v[0]; o[1]=(_Float16)v[1]; o[2]=(_Float16)v[2]; o[3]=(_Float16)v[3];
        ((f16x4*)(Wi16 + (size_t)row * kDM))[cv] = o;
      } else {
        const int h = row - 8192;    // dt row -> transposed f32 pack
        const f4 v = ((const f4*)(W_in + (size_t)(4096 + h * 129 + 128) * kDM))[cv];
        const int k = cv * 4;
        WdtT[(k + 0) * 32 + h] = v[0];
        WdtT[(k + 1) * 32 + h] = v[1];
        WdtT[(k + 2) * 32 + h] = v[2];
        WdtT[(k + 3) * 32 + h] = v[3];
      }
    } else {
      i -= kCvtX + kCvtW;
      const f4 v = ((const f4*)W_out)[i];
      f16x4 o; o[0]=(_Float16)v[0]; o[1]=(_Float16)v[1]; o[2]=(_Float16)v[2]; o[3]=(_Float16)v[3];
      ((f16x4*)Wo16)[i] = o;
    }
  } else {
    const int i = (bid - kCvtBlocks) * 256 + tid;
    if (i < 2048) negA[i] = -__expf(A_log[i]);
  }
}

// ---------------------------------------------------------------------------
// K1b: dtb = softplus(x @ Wdt^T + bias), f32 exact. 512 blocks x 4 rows.
// thread = (head h = tid&31, k-slice = tid>>5); WdtT reads are 128B-coalesced
// per 32-lane group; x rows staged in LDS; 8-slice LDS reduce.
// ---------------------------------------------------------------------------
__global__ __launch_bounds__(256) void dt_gemm(
    const float* __restrict__ x, const float* __restrict__ WdtT,
    const float* __restrict__ dt_bias, float* __restrict__ dtb) {
  __shared__ alignas(16) float Xs[4][1024];   // 16 KB
  __shared__ float Ps[4][8][32];              // 4 KB
  const int tid = threadIdx.x;
  const int gm0 = blockIdx.x * 4;
#pragma unroll
  for (int q = 0; q < 4; ++q)
    *(f4*)&Xs[q][tid * 4 - (tid >> 8)] = *(const f4*)(x + (size_t)(gm0 + q) * kDM + tid * 4);
  __syncthreads();

  const int h  = tid & 31;
  const int sl = tid >> 5;
  const int k0 = sl * 128;
  float p0 = 0.f, p1 = 0.f, p2 = 0.f, p3 = 0.f;
#pragma unroll 8
  for (int i = 0; i < 128; ++i) {
    const float w = WdtT[(k0 + i) * 32 + h];
    p0 = fmaf(Xs[0][k0 + i], w, p0);
    p1 = fmaf(Xs[1][k0 + i], w, p1);
    p2 = fmaf(Xs[2][k0 + i], w, p2);
    p3 = fmaf(Xs[3][k0 + i], w, p3);
  }
  Ps[0][sl][h] = p0; Ps[1][sl][h] = p1; Ps[2][sl][h] = p2; Ps[3][sl][h] = p3;
  __syncthreads();
  if (tid < 128) {
    const int r = tid >> 5, hh = tid & 31;
    float v = 0.f;
#pragma unroll
    for (int s2 = 0; s2 < 8; ++s2) v += Ps[r][s2][hh];
    const float dtp = v + dt_bias[hh];
    const float dt  = (dtp > 20.f) ? dtp : log1pf(__expf(dtp));
    const int gm = gm0 + r;
    dtb[(size_t)((gm >> 10) * 32 + hh) * kL + (gm & 1023)] = dt;
  }
}

// ---------------------------------------------------------------------------
// K2: f16 GEMM 128x128, BK=32, f16 out. proj16[2048,8192] = x16 @ Wi16^T.
// ---------------------------------------------------------------------------
__global__ __launch_bounds__(256) void gemm1(
    const _Float16* __restrict__ A, const _Float16* __restrict__ Bm,
    _Float16* __restrict__ C, int M, int N, int K) {
  __shared__ alignas(16) _Float16 As[128][32];
  __shared__ alignas(16) _Float16 Bs[128][32];
  const int tid  = threadIdx.x;
  const int lane = tid & 63;
  const int w    = tid >> 6;
  const int m0   = blockIdx.x * 128;
  const int n0   = blockIdx.y * 128;
  const int ra   = lane >> 2;
  const int cc   = (lane & 3) * 8;
  const int wm   = (w & 1) * 64;
  const int wn   = (w >> 1) * 64;
  const int l16  = lane & 15;
  const int l4   = lane >> 4;

  f4 acc[4][4] = {};

  for (int k0 = 0; k0 < K; k0 += 32) {
#pragma unroll
    for (int q = 0; q < 2; ++q) {
      const int row = (w * 2 + q) * 16 + ra;
      async_ld16(A + (size_t)(m0 + row) * K + (k0 + cc), &As[row][cc]);
      async_ld16(Bm + (size_t)(n0 + row) * K + (k0 + cc), &Bs[row][cc]);
    }
    __syncthreads();
    f16x8 af[4], bf[4];
#pragma unroll
    for (int t = 0; t < 4; ++t) {
      af[t] = *reinterpret_cast<const f16x8*>(&As[wm + t * 16 + l16][l4 * 8]);
      bf[t] = *reinterpret_cast<const f16x8*>(&Bs[wn + t * 16 + l16][l4 * 8]);
    }
#pragma unroll
    for (int i = 0; i < 4; ++i)
#pragma unroll
      for (int j = 0; j < 4; ++j)
        acc[i][j] = __builtin_amdgcn_mfma_f32_16x16x32_f16(af[i], bf[j], acc[i][j], 0, 0, 0);
    __syncthreads();
  }

  const int col = l16;      // C/D: col = lane&15, row = (lane>>4)*4 + reg
  const int r0  = l4 * 4;
#pragma unroll
  for (int i = 0; i < 4; ++i)
#pragma unroll
    for (int j = 0; j < 4; ++j) {
      const int gn = n0 + wn + j * 16 + col;
#pragma unroll
      for (int r = 0; r < 4; ++r) {
        const int gm = m0 + wm + i * 16 + r0 + r;
        C[(size_t)gm * N + gn] = (_Float16)acc[i][j][r];
      }
    }
}

// ---------------------------------------------------------------------------
// K3: scan pass 1. LDS: Ad f32 (exp at stage), Bd raw f16 (async copy),
// Xd = f16(silu(conv(x)) * dt). lane = d, wave w owns s in [16w,16w+16).
// ---------------------------------------------------------------------------
__global__ __launch_bounds__(256) void scan_pass1(
    const _Float16* __restrict__ proj16, const float* __restrict__ dtb,
    const float* __restrict__ negA, const float* __restrict__ conv_w,
    const float* __restrict__ conv_b, float* __restrict__ hloc,
    float* __restrict__ sdt) {
  __shared__ alignas(16) float Ad[kQ][64];       // 16 KB
  __shared__ alignas(16) _Float16 Bd[kQ][64];    // 8 KB
  __shared__ alignas(16) _Float16 Xd[kQ][64];    // 8 KB
  __shared__ float dts[kQ];
  const int tid  = threadIdx.x;
  const int bn   = blockIdx.x >> 4;
  const int c    = blockIdx.x & (kNC - 1);
  const int lane = tid & 63;
  const int w    = tid >> 6;
  const int b    = bn >> 5, n = bn & 31;
  const int l0   = c * kQ;

#pragma unroll
  for (int i = 0; i < 2; ++i) {
    const int row = i * 32 + (tid >> 3);
    const int ch  = (tid & 7) * 8;
    async_ld16(proj16 + (size_t)(b * kL + l0 + row) * kPROJW + 4096 + n * 64 + ch,
               &Bd[row][ch]);
  }
  {
    const int l  = tid >> 2;
    const int q4 = (tid & 3) * 16;
    const int gl = l0 + l;
    const float dtl = dtb[(size_t)bn * kL + gl];
    if ((tid & 3) == 0) dts[l] = dtl;
#pragma unroll
    for (int j = 0; j < 16; ++j)
      Ad[l][q4 + j] = __expf(negA[n * 64 + q4 + j] * dtl);
    float acc[16];
#pragma unroll
    for (int j = 0; j < 16; ++j) acc[j] = conv_b[n * 64 + q4 + j];
#pragma unroll
    for (int jj = 0; jj < 4; ++jj) {
      const int r = gl - 3 + jj;
      if (r < 0) continue;
      const _Float16* pX = proj16 + (size_t)(b * kL + r) * kPROJW + n * 64 + q4;
      const f16x8 v0 = *(const f16x8*)pX;
      const f16x8 v1 = *(const f16x8*)(pX + 8);
#pragma unroll
      for (int j = 0; j < 8; ++j) {
        acc[j]     += conv_w[(n * 64 + q4 + j) * 4 + jj]     * (float)v0[j];
        acc[8 + j] += conv_w[(n * 64 + q4 + 8 + j) * 4 + jj] * (float)v1[j];
      }
    }
    f16x8 o0, o1;
#pragma unroll
    for (int j = 0; j < 8; ++j) {
      const float a0 = acc[j], a1 = acc[8 + j];
      o0[j] = (_Float16)(dtl * a0 / (1.f + __expf(-a0)));
      o1[j] = (_Float16)(dtl * a1 / (1.f + __expf(-a1)));
    }
    *(f16x8*)&Xd[l][q4]     = o0;
    *(f16x8*)&Xd[l][q4 + 8] = o1;
  }
  __syncthreads();

  if (tid == 0) {
    float s = 0.f;
    for (int t = 0; t < kQ; ++t) s += dts[t];
    sdt[bn * kNC + c] = s;
  }

  float h[16];
#pragma unroll
  for (int j = 0; j < 16; ++j) h[j] = 0.f;

#pragma unroll 4
  for (int t = 0; t < kQ; ++t) {
    f4 a[4];
#pragma unroll
    for (int j = 0; j < 4; ++j) a[j] = ((const f4*)&Ad[t][w * 16])[j];
    const f16x8 b0 = *(const f16x8*)&Bd[t][w * 16];
    const f16x8 b1 = *(const f16x8*)&Bd[t][w * 16 + 8];
    const float xdt = (float)Xd[t][lane];
#pragma unroll
    for (int q = 0; q < 4; ++q)
#pragma unroll
      for (int j = 0; j < 4; ++j) {
        const int sj = q * 4 + j;
        const float bx = fmaf((float)(sj < 8 ? b0[sj & 7] : b1[sj & 7]), xdt, 0.f);
        h[sj] = fmaf(a[q][j], h[sj], bx);
      }
  }

  float* hp = hloc + (((size_t)bn * kNC + c) * 64 + w * 16) * 64 + lane;
#pragma unroll
  for (int j = 0; j < 16; ++j) hp[(size_t)j * 64] = h[j];
}

// ---------------------------------------------------------------------------
// K4: chunk stitching. h_in[c+1] = exp(negA_s * sdt[c]) * h_in[c] + hloc[c]
// ---------------------------------------------------------------------------
__global__ __launch_bounds__(256) void scan_pass2(
    const float* __restrict__ hloc, const float* __restrict__ sdt,
    const float* __restrict__ negA, float* __restrict__ hin) {
  const int bn = blockIdx.x >> 2;
  const int dq = blockIdx.x & 3;
  const int n  = bn & 31;
  const int s  = threadIdx.x >> 2;
  const int d0 = dq * 16 + (threadIdx.x & 3) * 4;
  const float Aa = negA[n * 64 + s];
  f4 h = {};
  for (int c = 0; c < kNC; ++c) {
    const size_t off = (((size_t)bn * kNC + c) * 64 + s) * 64 + d0;
    const float ap = __expf(Aa * sdt[bn * kNC + c]);
    *(f4*)(hin + off) = h;
    h = ap * h + *(const f4*)(hloc + off);
  }
}

// ---------------------------------------------------------------------------
// K5: scan pass 3. LDS: Ad f32, Bd/Cd/Zd raw f16, Xd = f16(x_silu*dt),
// rdt = 1/dt for epilogue. lane=(sg,dd), d = w*16+dd.
// ---------------------------------------------------------------------------
__global__ __launch_bounds__(256) void scan_pass3(
    const _Float16* __restrict__ proj16, const float* __restrict__ dtb,
    const float* __restrict__ negA, const float* __restrict__ conv_w,
    const float* __restrict__ conv_b, const float* __restrict__ hin,
    const float* __restrict__ Dv, _Float16* __restrict__ yin) {
  __shared__ alignas(16) float Ad[kQ][64];       // 16 KB
  __shared__ alignas(16) _Float16 Bd[kQ][64];    // 8 KB
  __shared__ alignas(16) _Float16 Cd[kQ][64];    // 8 KB
  __shared__ alignas(16) _Float16 Xd[kQ][64];    // 8 KB
  __shared__ alignas(16) _Float16 Zd[kQ][64];    // 8 KB
  __shared__ float rdt[kQ];
  const int tid  = threadIdx.x;
  const int bn   = blockIdx.x >> 4;
  const int c    = blockIdx.x & (kNC - 1);
  const int lane = tid & 63;
  const int w    = tid >> 6;
  const int sg   = lane >> 4;
  const int dd   = lane & 15;
  const int b    = bn >> 5, n = bn & 31;
  const int l0   = c * kQ;
  const int d    = w * 16 + dd;

#pragma unroll
  for (int i = 0; i < 2; ++i) {
    const int row = i * 32 + (tid >> 3);
    const int ch  = (tid & 7) * 8;
    const size_t rb = (size_t)(b * kL + l0 + row) * kPROJW + n * 64 + ch;
    async_ld16(proj16 + rb + 4096, &Bd[row][ch]);
    async_ld16(proj16 + rb + 6144, &Cd[row][ch]);
    async_ld16(proj16 + rb + 2048, &Zd[row][ch]);
  }
  {
    const int l  = tid >> 2;
    const int q4 = (tid & 3) * 16;
    const int gl = l0 + l;
    const float dtl = dtb[(size_t)bn * kL + gl];
    if ((tid & 3) == 0) rdt[l] = 1.0f / dtl;
#pragma unroll
    for (int j = 0; j < 16; ++j)
      Ad[l][q4 + j] = __expf(negA[n * 64 + q4 + j] * dtl);
    float acc[16];
#pragma unroll
    for (int j = 0; j < 16; ++j) acc[j] = conv_b[n * 64 + q4 + j];
#pragma unroll
    for (int jj = 0; jj < 4; ++jj) {
      const int r = gl - 3 + jj;
      if (r < 0) continue;
      const _Float16* pX = proj16 + (size_t)(b * kL + r) * kPROJW + n * 64 + q4;
      const f16x8 v0 = *(const f16x8*)pX;
      const f16x8 v1 = *(const f16x8*)(pX + 8);
#pragma unroll
      for (int j = 0; j < 8; ++j) {
        acc[j]     += conv_w[(n * 64 + q4 + j) * 4 + jj]     * (float)v0[j];
        acc[8 + j] += conv_w[(n * 64 + q4 + 8 + j) * 4 + jj] * (float)v1[j];
      }
    }
    f16x8 o0, o1;
#pragma unroll
    for (int j = 0; j < 8; ++j) {
      const float a0 = acc[j], a1 = acc[8 + j];
      o0[j] = (_Float16)(dtl * a0 / (1.f + __expf(-a0)));
      o1[j] = (_Float16)(dtl * a1 / (1.f + __expf(-a1)));
    }
    *(f16x8*)&Xd[l][q4]     = o0;
    *(f16x8*)&Xd[l][q4 + 8] = o1;
  }

  float h[16];
  const float* hp = hin + (((size_t)bn * kNC + c) * 64 + sg * 16) * 64 + d;
#pragma unroll
  for (int j = 0; j < 16; ++j) h[j] = hp[(size_t)j * 64];

  const float Dn = Dv[n];
  _Float16* Yb = yin + (size_t)(b * kL + l0) * kDI + n * 64 + d;
  __syncthreads();

#pragma unroll 4
  for (int t = 0; t < kQ; ++t) {
    f4 a[4];
#pragma unroll
    for (int j = 0; j < 4; ++j) a[j] = ((const f4*)&Ad[t][sg * 16])[j];
    const f16x8 b0 = *(const f16x8*)&Bd[t][sg * 16];
    const f16x8 b1 = *(const f16x8*)&Bd[t][sg * 16 + 8];
    const f16x8 c0 = *(const f16x8*)&Cd[t][sg * 16];
    const f16x8 c1 = *(const f16x8*)&Cd[t][sg * 16 + 8];
    const float xdt = (float)Xd[t][d];

    float pq[4];
#pragma unroll
    for (int q = 0; q < 4; ++q) {
      float p = 0.f;
#pragma unroll
      for (int j = 0; j < 4; ++j) {
        const int sj = q * 4 + j;
        const float bx = fmaf((float)(sj < 8 ? b0[sj & 7] : b1[sj & 7]), xdt, 0.f);
        h[sj] = fmaf(a[q][j], h[sj], bx);
        p = fmaf((float)(sj < 8 ? c0[sj & 7] : c1[sj & 7]), h[sj], p);
      }
      pq[q] = p;
    }
    float p = (pq[0] + pq[1]) + (pq[2] + pq[3]);
    p += __shfl_xor(p, 16);
    p += __shfl_xor(p, 32);
    if (sg == 0) {
      const float xt = xdt * rdt[t];
      const float z = (float)Zd[t][d];
      const float zs = z / (1.f + __expf(-z));
      Yb[(size_t)t * kDI] = (_Float16)((p + Dn * xt) * zs);
    }
  }
}

// ---------------------------------------------------------------------------
// K6: out[2048,1024] f32 = yin @ Wo16^T. 64x64 tile, BK=32, 512 blocks.
// ---------------------------------------------------------------------------
__global__ __launch_bounds__(256) void gemm_out(
    const _Float16* __restrict__ A, const _Float16* __restrict__ Bm,
    float* __restrict__ C) {
  __shared__ alignas(16) _Float16 As[64][32];
  __shared__ alignas(16) _Float16 Bs[64][32];
  const int tid  = threadIdx.x;
  const int lane = tid & 63;
  const int w    = tid >> 6;
  const int m0   = blockIdx.x * 64;
  const int n0   = blockIdx.y * 64;
  const int row  = tid >> 2;
  const int cc   = (tid & 3) * 8;
  const int wm   = (w & 1) * 32;
  const int wn   = (w >> 1) * 32;
  const int l16  = lane & 15;
  const int l4   = lane >> 4;

  f4 acc[2][2] = {};

  for (int k0 = 0; k0 < kDI; k0 += 32) {
    async_ld16(A + (size_t)(m0 + row) * kDI + (k0 + cc), &As[row][cc]);
    async_ld16(Bm + (size_t)(n0 + row) * kDI + (k0 + cc), &Bs[row][cc]);
    __syncthreads();
    f16x8 af[2], bf[2];
#pragma unroll
    for (int t = 0; t < 2; ++t) {
      af[t] = *reinterpret_cast<const f16x8*>(&As[wm + t * 16 + l16][l4 * 8]);
      bf[t] = *reinterpret_cast<const f16x8*>(&Bs[wn + t * 16 + l16][l4 * 8]);
    }
#pragma unroll
    for (int i = 0; i < 2; ++i)
#pragma unroll
      for (int j = 0; j < 2; ++j)
        acc[i][j] = __builtin_amdgcn_mfma_f32_16x16x32_f16(af[i], bf[j], acc[i][j], 0, 0, 0);
    __syncthreads();
  }

  const int col = l16;
  const int r0  = l4 * 4;
#pragma unroll
  for (int i = 0; i < 2; ++i)
#pragma unroll
    for (int j = 0; j < 2; ++j) {
      const int gn = n0 + wn + j * 16 + col;
#pragma unroll
      for (int r = 0; r < 4; ++r) {
        const int gm = m0 + wm + i * 16 + r0 + r;
        C[(size_t)gm * kDM + gn] = acc[i][j][r];
      }
    }
}

// ---------------------------------------------------------------------------
extern "C" void kernel_launch(void* const* d_in, const int* in_sizes, int n_in,
                              void* d_out, int out_size, void* d_ws, size_t ws_size,
                              hipStream_t stream) {
  const float* x      = (const float*)d_in[0];
  const float* W_in   = (const float*)d_in[1];
  const float* conv_w = (const float*)d_in[2];
  const float* conv_b = (const float*)d_in[3];
  const float* A_log  = (const float*)d_in[4];
  const float* Dv     = (const float*)d_in[5];
  const float* dt_b   = (const float*)d_in[6];
  const float* W_out  = (const float*)d_in[7];
  float* out = (float*)d_out;

  char* p = (char*)d_ws;
  _Float16* proj16 = (_Float16*)p; p += (size_t)kBL * kPROJW * 2;   // 33.6 MB
  float* dtb   = (float*)p; p += (size_t)64 * kL * 4;
  float* negA  = (float*)p; p += 2048 * 4;
  float* WdtT  = (float*)p; p += (size_t)1024 * 32 * 4;             // 128 KB
  float* sdt   = (float*)p; p += 64 * kNC * 4 + 3968;               // pad
  float* hloc  = (float*)p; p += (size_t)64 * kNC * 64 * 64 * 4;    // 16.8 MB
  float* hin   = (float*)p; p += (size_t)64 * kNC * 64 * 64 * 4;    // 16.8 MB
  _Float16* yin  = (_Float16*)p; p += (size_t)kBL * kDI * 2;        // 8.4 MB
  _Float16* Wo16 = (_Float16*)p; p += (size_t)kDM * kDI * 2;        // 4.2 MB
  _Float16* x16  = (_Float16*)hloc;                 // alias (pre-scan phase)
  _Float16* Wi16 = x16 + (size_t)kBL * kDM;         // 16.8 MB (tail in hin)

  prep_inputs<<<kCvtBlocks + kNegABlocks, 256, 0, stream>>>(
      x, W_in, W_out, A_log, x16, Wi16, Wo16, WdtT, negA);

  dt_gemm<<<kBL / 4, 256, 0, stream>>>(x, WdtT, dt_b, dtb);

  gemm1<<<dim3(kBL / 128, kPROJW / 128), 256, 0, stream>>>(
      x16, Wi16, proj16, kBL, kPROJW, kDM);

  scan_pass1<<<64 * kNC, 256, 0, stream>>>(proj16, dtb, negA, conv_w, conv_b, hloc, sdt);
  scan_pass2<<<256, 256, 0, stream>>>(hloc, sdt, negA, hin);
  scan_pass3<<<64 * kNC, 256, 0, stream>>>(proj16, dtb, negA, conv_w, conv_b, hin, Dv, yin);

  gemm_out<<<dim3(kBL / 64, kDM / 64), 256, 0, stream>>>(yin, Wo16, out);
}